// Round 1
// baseline (884.698 us; speedup 1.0000x reference)
//
#include <hip/hip_runtime.h>

// Soft-DTW (gamma=1), batched 64 x (1024 vs 1024, 2-D points), anti-diagonal
// wavefront. One block per batch element, 256 threads, thread t owns DP rows
// 4t..4t+3 (R=4 coarsening).
//
// Recurrence (diagonal d, row i, col j = d-i):
//   R_d[i] = D[i,j] + softmin( R_{d-2}[i-1],   // diagonal
//                              R_{d-1}[i-1],   // up    (reference "right")
//                              R_{d-1}[i]   )  // left  (reference "down")
// Per-cell op order is IDENTICAL to the previous (bit-exact, passing) kernel.
//
// Coarsening: cells r=1..3 take their row i-1 predecessors from this thread's
// own registers (cur/old of cell r-1). Only cell r=0 needs the left-neighbor
// thread's last row: passed by __shfl_up within a wave, and through a tiny
// double-buffered LDS slot across the 3 wave boundaries (one 4-wave
// __syncthreads per diagonal -- down from a 16-wave barrier + LDS round-trip
// per diagonal in the previous version, which was ~2/3 of its runtime:
// VALUBusy was 15%, issue work ~230 cyc of the measured 627 cyc/diagonal).
//
// Scheduling inside a step: nf3 is computed FIRST (it feeds the neighbor
// exchange), nf0 LAST (it consumes the LDS/global values read just after the
// previous barrier), giving ~3 cells of slack to hide LDS/L1 latency.
//
// Race-freedom of bnd[d&1]: written pre-barrier at step d, read post-barrier
// at step d; next write to the same parity is at d+2, which every thread
// reaches only after barrier d+1, which the reader passes only after its
// step-d read. One barrier per diagonal suffices.

#define N 1024
#define NDIAG (2 * N - 1) // 2047
#define TPB 256

__device__ __forceinline__ float sqdist2(float2 a, float2 b) {
    float dx = a.x - b.x;
    float dy = a.y - b.y;
    return dx * dx + dy * dy;
}

// EXACT same op order as the baseline kernel (bit-compatible):
__device__ __forceinline__ float softdtw_cell(float2 sp, float2 cp,
                                              float mp,  // R_{d-1}[i]
                                              float a,   // R_{d-1}[i-1]
                                              float b2)  // R_{d-2}[i-1]
{
    float dx = sp.x - cp.x;
    float dy = sp.y - cp.y;
    float cost = dx * dx + dy * dy;
    float m = fminf(fminf(mp, a), b2);
    // m finite for every active cell; __expf(-inf)=0 handles boundaries.
    float s = __expf(m - mp) + __expf(m - a) + __expf(m - b2);
    return cost + m - __logf(s);
}

__global__ __launch_bounds__(TPB) void dtw_kernel(
    const float2* __restrict__ snake,
    const float2* __restrict__ contour,
    float* __restrict__ out)
{
    const int b = blockIdx.x;
    const int t = threadIdx.x;
    const int lane = t & 63;
    const int w = t >> 6;
    const float INF = __builtin_inff();

    __shared__ float bnd[2][TPB / 64]; // wave-boundary R values, double-buffered

    const float2* sg = snake + (size_t)b * N;
    const float2* cg = contour + (size_t)b * N;

    const int i0 = 4 * t; // first row owned by this thread

    // Snake points: register-resident for the whole kernel (coalesced load).
    float2 sp0 = sg[i0 + 0];
    float2 sp1 = sg[i0 + 1];
    float2 sp2 = sg[i0 + 2];
    float2 sp3 = sg[i0 + 3];

    // Contour sliding window: cwr = contour[(d - i0 - r) mod N], entering d=2.
    // Wrapped (out-of-range) entries are in-bounds garbage, guarded by the
    // per-cell active test. Contour (8 KB) stays L1-resident; 1 load/step.
    float2 cw0 = cg[(2 - i0) & (N - 1)];
    float2 cw1 = cg[(1 - i0) & (N - 1)];
    float2 cw2 = cg[(0 - i0) & (N - 1)];
    float2 cw3 = cg[(-1 - i0) & (N - 1)];

    // cur[r] = R_{d-1}[i0+r], old[r] = R_{d-2}[i0+r]  (INF when out of range)
    float cur0 = INF, cur1 = INF, cur2 = INF, cur3 = INF;
    float old0 = INF, old1 = INF, old2 = INF, old3 = INF;
    float nb1 = INF;  // R_{d-1}[i0-1] (left neighbor's last row)
    float nb2 = INF;  // R_{d-2}[i0-1]

    if (t == 0) {
        // Diagonals 0 and 1 (reference `init`):
        //   R0[0] = D(0,0);  R1[0] = D(0,1)+D(0,0);  R1[1] = D(1,0)+D(0,0)
        float2 c0 = cg[0], c1 = cg[1];
        float d00 = sqdist2(sp0, c0);
        old0 = d00;
        cur0 = sqdist2(sp0, c1) + d00;
        cur1 = sqdist2(sp1, c0) + d00;
    }

    #pragma unroll 2
    for (int d = 2; d < NDIAG; ++d) {
        // r = 3 first: its result feeds the neighbor exchange.
        float nf3 = INF;
        if ((unsigned)(d - (i0 + 3)) < (unsigned)N)
            nf3 = softdtw_cell(sp3, cw3, cur3, cur2, old2);
        float up = __shfl_up(nf3, 1);           // intra-wave neighbor pass
        if (lane == 63) bnd[d & 1][w] = nf3;    // wave-boundary pass

        float nf2 = INF, nf1 = INF, nf0 = INF;
        if ((unsigned)(d - (i0 + 2)) < (unsigned)N)
            nf2 = softdtw_cell(sp2, cw2, cur2, cur1, old1);
        if ((unsigned)(d - (i0 + 1)) < (unsigned)N)
            nf1 = softdtw_cell(sp1, cw1, cur1, cur0, old0);
        if ((unsigned)(d - i0) < (unsigned)N)
            nf0 = softdtw_cell(sp0, cw0, cur0, nb1, nb2);

        __syncthreads();
        // Issued right after the barrier, consumed LAST next iteration (nf0):
        if (lane == 0) up = (w == 0) ? INF : bnd[d & 1][w - 1];
        float2 nc = cg[((d + 1) - i0) & (N - 1)];

        // Rotate state one diagonal.
        nb2 = nb1; nb1 = up;
        old0 = cur0; old1 = cur1; old2 = cur2; old3 = cur3;
        cur0 = nf0;  cur1 = nf1;  cur2 = nf2;  cur3 = nf3;
        cw3 = cw2; cw2 = cw1; cw1 = cw0; cw0 = nc;
    }

    // Thread 255's cur3 holds R[1023,1023] (written at d = 2046).
    if (t == TPB - 1) {
        atomicAdd(out, cur3 * (1.0f / 64.0f));
    }
}

extern "C" void kernel_launch(void* const* d_in, const int* in_sizes, int n_in,
                              void* d_out, int out_size, void* d_ws, size_t ws_size,
                              hipStream_t stream) {
    const float2* snake   = (const float2*)d_in[0];
    const float2* contour = (const float2*)d_in[1];
    float* out = (float*)d_out;
    // Harness re-poisons d_out to 0xAA before every timed launch.
    hipMemsetAsync(out, 0, sizeof(float), stream);
    dtw_kernel<<<64, TPB, 0, stream>>>(snake, contour, out);
}

// Round 2
// 593.567 us; speedup vs baseline: 1.4905x; 1.4905x over previous
//
#include <hip/hip_runtime.h>

// Soft-DTW (gamma=1), batched 64 x (1024 vs 1024, 2-D points).
// One block per batch element, 1024 threads (16 waves), thread t = DP row t.
//
// Recurrence (diagonal d, row i, col j = d-i):
//   R_d[i] = D[i,j] + softmin( R_{d-2}[i-1],   // diagonal
//                              R_{d-1}[i-1],   // up
//                              R_{d-1}[i]   )  // left
// Per-cell op order IDENTICAL to the previous passing kernels (bit-exact).
//
// === Skewed-wave pipeline (this round's change) ===
// Previous versions paid one 16-wave __syncthreads + a critical-path LDS read
// PER DIAGONAL (627 cyc/step vs ~230 cyc of issue).  The row dependency is
// one-directional (row i needs only rows i-1, i), so wave w (rows 64w..64w+63)
// runs K=8 diagonals BEHIND wave w-1.  Wave w-1 publishes its boundary row
// (64w-1) value for diagonal d into an LDS ring slot ring[w-1][d & 63]; wave w
// reads that slot K global steps later.  With one __syncthreads every K steps,
// every ring read in epoch E was written in epoch <= E-1 (writer is exactly K
// steps ahead), and a slot is rewritten only 64 diagonals later (64-K >= K
// steps after the read, so a barrier separates read from overwrite).
// Intra-wave neighbor passing is pure __shfl_up (lockstep, no sync).
//
// Ring slots are pre-initialized to INF: a reader's "early" reads (one step
// before its first active diagonal, supplying nb2 = R[i-1][-1] = INF for the
// j=0 cell) hit never-yet-written slots, and the writer cannot have wrapped
// into them (wrap distance 64 > K).  Writes are predicated on row-activity.
//
// Wave execute window: d in [64w-1, 64w+1086] (the -1 pre-step performs the
// first ring read).  Outside the window the wave skips the body (uniform
// branch) but still reaches every barrier.  Pipeline fill/drain costs
// (NWAVES-1)*K = 120 extra global steps (~6%).
//
// Cost of softmin kept bit-exact: m = min3; s = sum of 3 __expf; r = cost+m-__logf(s).

#define N 1024
#define NDIAG (2 * N - 1)       // 2047
#define TPB 1024
#define NWAVES (TPB / 64)       // 16
#define K 8                     // diagonals per barrier epoch
// global steps needed: tau = 0 .. (2046-2) + (NWAVES-1)*K  -> 2045+120 = 2165
#define TOTAL (NDIAG - 2 + (NWAVES - 1) * K)   // 2165
#define NGRP ((TOTAL + K - 1) / K)             // 271

__device__ __forceinline__ float sqdist2(float2 a, float2 b) {
    float dx = a.x - b.x;
    float dy = a.y - b.y;
    return dx * dx + dy * dy;
}

__global__ __launch_bounds__(TPB) void dtw_kernel(
    const float2* __restrict__ snake,
    const float2* __restrict__ contour,
    float* __restrict__ out)
{
    const int b = blockIdx.x;
    const int t = threadIdx.x;
    const int lane = t & 63;
    const int w = t >> 6;
    const float INF = __builtin_inff();

    __shared__ float2 c[N];             // contour points (8 KB)
    __shared__ float ring[NWAVES][64];  // boundary ring: ring[w] written by wave w
    __shared__ float initvals[3];       // R0[0], R1[0], R1[1]

    const float2* sg = snake + (size_t)b * N;
    const float2* cg = contour + (size_t)b * N;

    const float2 sp = sg[t];            // snake point: register-resident
    c[t] = cg[t];
    ((float*)ring)[t] = INF;            // 16*64 = 1024 slots, one per thread
    if (t == 0) {
        // Diagonals 0 and 1 (reference `init`):
        //   R0[0] = D(0,0);  R1[0] = D(0,1)+D(0,0);  R1[1] = D(1,0)+D(0,0)
        float2 s0 = sg[0], s1 = sg[1];
        float2 c0 = cg[0], c1 = cg[1];
        float d00 = sqdist2(s0, c0);
        initvals[0] = d00;
        initvals[1] = sqdist2(s0, c1) + d00;
        initvals[2] = sqdist2(s1, c0) + d00;
    }
    __syncthreads();

    // Register state entering the wave's first executed step:
    //   cur = R_{d-1}[t], nb1 = R_{d-1}[t-1], nb2 = R_{d-2}[t-1]
    float cur = INF, nb1 = INF, nb2 = INF;
    if (t == 0) {
        cur = initvals[1];
    } else if (t == 1) {
        cur = initvals[2];
        nb1 = initvals[1];
        nb2 = initvals[0];
    } else if (t == 2) {
        nb1 = initvals[2];
    }

    // Wave-local diagonal at global step tau: d = tau + 2 - K*w.
    int d = 2 - K * w;
    const int lo = (w == 0) ? 2 : (64 * w - 1);    // -1 pre-step: first ring read
    const int hi = 64 * w + 63 + (N - 1);          // 64w + 1086

    for (int g = 0; g < NGRP; ++g) {
        #pragma unroll
        for (int k = 0; k < K; ++k) {
            const int dk = d + k;
            if (dk >= lo && dk <= hi) {            // wave-uniform window test
                const unsigned u = (unsigned)(dk - t);
                const bool act = u < (unsigned)N;
                const float2 cp = c[u & (N - 1)];
                float nf = INF;
                if (act) {
                    float dx = sp.x - cp.x;
                    float dy = sp.y - cp.y;
                    float cost = dx * dx + dy * dy;
                    float m = fminf(fminf(cur, nb1), nb2);
                    // m finite for every active cell; __expf(-inf)=0 exact.
                    float s = __expf(m - cur) + __expf(m - nb1)
                            + __expf(m - nb2);
                    nf = cost + m - __logf(s);
                    cur = nf;
                }
                if (lane == 63 && act) ring[w][dk & 63] = nf;
                float up = __shfl_up(nf, 1);
                float rv = INF;
                if (lane == 0 && w > 0) rv = ring[w - 1][dk & 63];
                nb2 = nb1;
                nb1 = (lane == 0) ? rv : up;
            }
        }
        d += K;
        __syncthreads();                           // one barrier per K diagonals
    }

    // Thread 1023 (wave 15, lane 63): cur holds R[1023,1023] (diag 2046).
    if (t == TPB - 1) {
        atomicAdd(out, cur * (1.0f / 64.0f));
    }
}

extern "C" void kernel_launch(void* const* d_in, const int* in_sizes, int n_in,
                              void* d_out, int out_size, void* d_ws, size_t ws_size,
                              hipStream_t stream) {
    const float2* snake   = (const float2*)d_in[0];
    const float2* contour = (const float2*)d_in[1];
    float* out = (float*)d_out;
    // Harness re-poisons d_out to 0xAA before every timed launch.
    hipMemsetAsync(out, 0, sizeof(float), stream);
    dtw_kernel<<<64, TPB, 0, stream>>>(snake, contour, out);
}

// Round 3
// 571.826 us; speedup vs baseline: 1.5471x; 1.0380x over previous
//
#include <hip/hip_runtime.h>

// Soft-DTW (gamma=1), batched 64 x (1024 vs 1024, 2-D points).
// One block per batch element, 1024 threads (16 waves), thread t = DP row t.
//
// Recurrence (diagonal d, row i, col j = d-i):
//   R_d[i] = D[i,j] + softmin( R_{d-2}[i-1], R_{d-1}[i-1], R_{d-1}[i] )
// Per-cell op order IDENTICAL to all previous passing kernels (bit-exact).
//
// === Register-resident steady state (this round's change) ===
// R0/R1/R2 all landed at ~600 cyc/diagonal regardless of barrier frequency.
// Diagnosis: every step's neighbor exchange hit the per-CU LDS pipe
// (__shfl_up = ds_bpermute + ring/contour LDS reads) and serialized each wave
// on lgkmcnt (~120cyc) ON the dependency chain. This version makes the
// steady-state step pure-register:
//   - intra-wave shift-by-1 via VALU DPP: row_shr:1 (0x111) for lanes %16!=0,
//     row_bcast15 (0x142) for lanes 16/32/48, cndmask to merge. No LDS.
//   - wave-boundary ring batched PER EPOCH (K=8 diagonals): thanks to the
//     K-step skew, wave w-1's 8 boundary values for my epoch are complete
//     before the epoch barrier. Lane 63 writes 2x ds_write_b128 at epoch end;
//     lane 0 reads 2x ds_read_b128 at epoch start. Epoch-parity double
//     buffer; race-free by the per-epoch __syncthreads.
//   - contour points from registers: each lane needs 8 consecutive float2 per
//     epoch; prefetched from global (L1-resident, 8 KB/batch) at the bottom
//     of the previous epoch. LDS contour staging removed.
//
// Skew recap: wave w runs K=8 diagonals behind wave w-1. Wave w at epoch g,
// step k computes diag dk = 8g+k+2-8w and (lane 0) consumes the boundary
// value wave w-1 produced for the SAME dk at ITS epoch g-1, step k ->
// ring[w-1][(g-1)&1][k]. Slots for diags outside the writer's window carry
// stale/INF values; the reader's cells at those diags are provably inactive.
// Ring pre-init to INF covers the fill phase (nb2 = INF boundary cases).

#define N 1024
#define TPB 1024
#define NWAVES (TPB / 64)                      // 16
#define K 8                                    // diagonals per epoch
#define TOTAL (2 * N - 3 + (NWAVES - 1) * K)   // 2045 + 120 = 2165 steps
#define NGRP ((TOTAL + K - 1) / K)             // 271 epochs

__device__ __forceinline__ float sqdist2(float2 a, float2 b) {
    float dx = a.x - b.x;
    float dy = a.y - b.y;
    return dx * dx + dy * dy;
}

// DPP move: dst lane gets src from dpp-selected lane; invalid lanes keep old.
template <int CTRL>
__device__ __forceinline__ float dpp_mov(float src, float old) {
    int r = __builtin_amdgcn_update_dpp(__float_as_int(old),
                                        __float_as_int(src),
                                        CTRL, 0xF, 0xF, false);
    return __int_as_float(r);
}

__global__ __launch_bounds__(TPB) void dtw_kernel(
    const float2* __restrict__ snake,
    const float2* __restrict__ contour,
    float* __restrict__ out)
{
    const int b = blockIdx.x;
    const int t = threadIdx.x;
    const int lane = t & 63;
    const int w = t >> 6;
    const float INF = __builtin_inff();

    __shared__ float ring[NWAVES][2][K];   // [writer wave][epoch parity][k]
    __shared__ float initvals[3];          // R0[0], R1[0], R1[1]

    const float2* sg = snake + (size_t)b * N;
    const float2* cg = contour + (size_t)b * N;

    const float2 sp = sg[t];               // snake point: register-resident

    if (t < NWAVES * 2 * K) ((float*)ring)[t] = INF;
    if (t == 0) {
        // Diagonals 0 and 1 (reference `init`):
        //   R0[0] = D(0,0);  R1[0] = D(0,1)+D(0,0);  R1[1] = D(1,0)+D(0,0)
        float2 s0 = sg[0], s1 = sg[1];
        float2 c0 = cg[0], c1 = cg[1];
        float d00 = sqdist2(s0, c0);
        initvals[0] = d00;
        initvals[1] = sqdist2(s0, c1) + d00;
        initvals[2] = sqdist2(s1, c0) + d00;
    }
    __syncthreads();

    // Register state entering the wave's first executed step:
    //   cur = R_{d-1}[t], nb1 = R_{d-1}[t-1], nb2 = R_{d-2}[t-1]
    float cur = INF, nb1 = INF, nb2 = INF;
    if (t == 0) {
        cur = initvals[1];
    } else if (t == 1) {
        cur = initvals[2];
        nb1 = initvals[1];
        nb2 = initvals[0];
    } else if (t == 2) {
        nb1 = initvals[2];
    }

    const int lo = (w == 0) ? 2 : (64 * w - 1);  // -1 pre-step seeds nb1
    const int hi = 64 * w + 63 + (N - 1);        // 64w + 1086
    int d0 = 2 - K * w;                          // diag of step k=0, epoch 0

    // Contour window for epoch 0: cw[k] = contour[(d0+k - t) mod N].
    // Wrapped entries are in-bounds garbage, guarded by the per-cell test.
    float2 cw[K];
    #pragma unroll
    for (int k = 0; k < K; ++k)
        cw[k] = cg[(unsigned)(d0 + k - t) & (N - 1)];

    float rv[K];                                 // ring values (lane 0 only)
    #pragma unroll
    for (int k = 0; k < K; ++k) rv[k] = INF;
    float wb[K];                                 // boundary values (lane 63)

    for (int g = 0; g < NGRP; ++g) {
        const bool overlap = (d0 <= hi) && (d0 + (K - 1) >= lo);

        // Epoch-start ring read: wave w-1's epoch g-1 slots, parity (g^1)&1.
        if (overlap && w > 0 && lane == 0) {
            const float4* p = (const float4*)&ring[w - 1][(g ^ 1) & 1][0];
            float4 A = p[0], B = p[1];
            rv[0] = A.x; rv[1] = A.y; rv[2] = A.z; rv[3] = A.w;
            rv[4] = B.x; rv[5] = B.y; rv[6] = B.z; rv[7] = B.w;
        }

        #pragma unroll
        for (int k = 0; k < K; ++k) {
            const int dk = d0 + k;
            if (dk >= lo && dk <= hi) {          // wave-uniform window test
                const bool act = (unsigned)(dk - t) < (unsigned)N;
                float nf = INF;
                if (act) {
                    float dx = sp.x - cw[k].x;
                    float dy = sp.y - cw[k].y;
                    float cost = dx * dx + dy * dy;
                    float m = fminf(fminf(cur, nb1), nb2);
                    // m finite for every active cell; __expf(-inf)=0 exact.
                    float s = __expf(m - cur) + __expf(m - nb1)
                            + __expf(m - nb2);
                    nf = cost + m - __logf(s);
                    cur = nf;
                }
                wb[k] = nf;
                // shift-up-by-1 across the wave, pure VALU (no LDS):
                float a  = dpp_mov<0x111>(nf, INF);  // row_shr:1
                float bc = dpp_mov<0x142>(nf, INF);  // row_bcast15
                float up = ((t & 15) == 0) ? bc : a;
                nb2 = nb1;
                nb1 = (lane == 0) ? rv[k] : up;
            }
        }

        // Epoch-end ring write: this wave's 8 boundary values, parity g&1.
        if (overlap && lane == 63) {
            float4* p = (float4*)&ring[w][g & 1][0];
            p[0] = make_float4(wb[0], wb[1], wb[2], wb[3]);
            p[1] = make_float4(wb[4], wb[5], wb[6], wb[7]);
        }

        d0 += K;

        // Prefetch contour window for the next epoch (consumed after the
        // barrier -> latency hidden under barrier + epoch-start overhead).
        #pragma unroll
        for (int k = 0; k < K; ++k)
            cw[k] = cg[(unsigned)(d0 + k - t) & (N - 1)];

        __syncthreads();
    }

    // Thread 1023 (wave 15, lane 63): cur holds R[1023,1023] (diag 2046).
    if (t == TPB - 1) {
        atomicAdd(out, cur * (1.0f / 64.0f));
    }
}

extern "C" void kernel_launch(void* const* d_in, const int* in_sizes, int n_in,
                              void* d_out, int out_size, void* d_ws, size_t ws_size,
                              hipStream_t stream) {
    const float2* snake   = (const float2*)d_in[0];
    const float2* contour = (const float2*)d_in[1];
    float* out = (float*)d_out;
    // Harness re-poisons d_out to 0xAA before every timed launch.
    hipMemsetAsync(out, 0, sizeof(float), stream);
    dtw_kernel<<<64, TPB, 0, stream>>>(snake, contour, out);
}

// Round 8
// 503.816 us; speedup vs baseline: 1.7560x; 1.1350x over previous
//
#include <hip/hip_runtime.h>

// Soft-DTW (gamma=1), batched 64 x (1024 vs 1024, 2-D points).
// One block per batch element, 1024 threads (16 waves), thread t = DP row t.
//
// === Exp-domain recurrence, FP64 state, PER-WAVE offset ===
// R0-R3: ~600 cyc/step regardless of barrier/exchange => serial softmin chain
// (v_exp+v_log on the dep chain) is the limiter. Exp2-domain:
//   Z = 2^(off - R*log2e)  =>  Z_d[i] = 2^(-D*log2e) * (Zdiag + Zup + Zleft)
// Chain per step: add+add+mul (f64) + DPP + select. ZERO transcendentals
// on-chain; the 2^(-D') factors are precomputed per epoch from prefetched
// points (f32 exp2, widened).
//
// Why fp64 + per-wave offset (R6/R7 post-mortems):
//  - fp32 + per-WAVE offset failed (R6): within-wave R-spread ~370 bits >
//    fp32's ~190-bit usable window -> boundary row underflowed in the
//    writer's own representation.
//  - fp32 + per-LANE offsets failed (R7): the DPP offset exchange reads
//    pre-copy offsets; during activation cascades (8 rows/epoch vs 1
//    lane/epoch offset propagation) a lane converts its feeder's zn with a
//    STALE offset -> mis-scaled handoff -> collapse. Structural, not tunable.
//  - fp64's ~2046-bit exponent window swallows spread (~400b) + growth
//    (~100b/epoch) with huge margin => ONE wave-uniform offset suffices.
//    Intra-wave DPP handoffs then need NO conversion (this exact exchange
//    was verified bit-exact in R2/R3); only lane 0's ring values get an
//    epoch-constant 2^(off-oin) factor, folded off-chain into rvc[].
//  - No per-lane special cases: cur = zn unconditionally. Inactive cells
//    have k2=0 -> zn=0, so pre-start AND finished lanes sit at exactly 0 and
//    drop out of the exponent-max rescale naturally. The final cell is
//    snapshotted to (res, res_off) at its own step, immune to later
//    rescales (fixes R6 bug a).
//
// Rescale (per epoch, exact): e_max = wave-max biased exponent of cur;
// sh = 1023 - e_max; state *= 2^sh (two-stage, clamped +-1022); off += sh.
// Ring: stores RAW fp64 zn of lane 63 (writer's boundary row) + writer's
// off; reader converts by 2^(off - oin), two-stage.
//
// Skew/ring/epoch protocol (bit-exact-verified in R2/R3, unchanged): wave w
// runs K=8 diags behind wave w-1; at epoch g step k it is at dk=8g+k+2-8w
// and reads ring[w-1][(g^1)&1][k], written by wave w-1 at its epoch g-1 for
// the SAME dk (one barrier between write and read; overwrite two barriers
// later). One __syncthreads per epoch.
//
// Final: R = (res_off - log2(res)) * ln2; loss = mean over batch.

#define N 1024
#define TPB 1024
#define NWAVES (TPB / 64)                      // 16
#define K 8                                    // diagonals per epoch
#define TOTAL (2 * N - 3 + (NWAVES - 1) * K)   // 2045 + 120 = 2165 steps
#define NGRP ((TOTAL + K - 1) / K)             // 271 epochs
#define L2E 1.442695040888963f
#define LN2D 0.6931471805599453

__device__ __forceinline__ float sqdist2(float2 a, float2 b) {
    float dx = a.x - b.x;
    float dy = a.y - b.y;
    return dx * dx + dy * dy;
}

// 64-bit DPP move (two 32-bit halves, same lane pattern; invalid lanes -> 0).
template <int CTRL>
__device__ __forceinline__ double dpp_movd(double src) {
    long long s = __double_as_longlong(src);
    int lo = __builtin_amdgcn_update_dpp(0, (int)(s & 0xffffffffLL),
                                         CTRL, 0xF, 0xF, false);
    int hi = __builtin_amdgcn_update_dpp(0, (int)(s >> 32),
                                         CTRL, 0xF, 0xF, false);
    return __longlong_as_double(((long long)hi << 32) | (unsigned int)lo);
}

// exact 2^s as double for s in [-1022, 1023]
__device__ __forceinline__ double pow2d(int s) {
    return __longlong_as_double((long long)(1023 + s) << 52);
}

__global__ __launch_bounds__(TPB) void dtw_kernel(
    const float2* __restrict__ snake,
    const float2* __restrict__ contour,
    float* __restrict__ out)
{
    const int b = blockIdx.x;
    const int t = threadIdx.x;
    const int lane = t & 63;
    const int w = t >> 6;

    __shared__ double ringv[NWAVES][2][K];  // [writer wave][epoch parity][k]
    __shared__ int    ringo[NWAVES][2];     // writer's (pre-rescale) off
    __shared__ float  initvals[3];          // R0[0], R1[0], R1[1]

    const float2* sg = snake + (size_t)b * N;
    const float2* cg = contour + (size_t)b * N;

    const float2 sp = sg[t];               // snake point: register-resident

    if (t < NWAVES * 2 * K) ((double*)ringv)[t] = 0.0;   // Z(INF) = 0
    if (t < NWAVES * 2)     ((int*)ringo)[t] = 0;
    if (t == 0) {
        // Diagonals 0 and 1 (reference `init`):
        //   R0[0] = D(0,0);  R1[0] = D(0,1)+D(0,0);  R1[1] = D(1,0)+D(0,0)
        float2 s0 = sg[0], s1 = sg[1];
        float2 c0 = cg[0], c1 = cg[1];
        float d00 = sqdist2(s0, c0);
        initvals[0] = d00;
        initvals[1] = sqdist2(s0, c1) + d00;
        initvals[2] = sqdist2(s1, c0) + d00;
    }
    __syncthreads();

    // Z-state entering the wave's first executed step (wave off = 0):
    //   cur = Z_{d-1}[t], nb1 = Z_{d-1}[t-1], nb2 = Z_{d-2}[t-1]
    double cur = 0.0, nb1 = 0.0, nb2 = 0.0;
    int off = 0;
    bool adopted = (w == 0);               // wave 0 has no upstream offset
    if (t == 0) {
        cur = (double)__builtin_amdgcn_exp2f(-L2E * initvals[1]);
    } else if (t == 1) {
        cur = (double)__builtin_amdgcn_exp2f(-L2E * initvals[2]);
        nb1 = (double)__builtin_amdgcn_exp2f(-L2E * initvals[1]);
        nb2 = (double)__builtin_amdgcn_exp2f(-L2E * initvals[0]);
    } else if (t == 2) {
        nb1 = (double)__builtin_amdgcn_exp2f(-L2E * initvals[2]);
    }

    double res = 1.0;                      // snapshot of my row's final cell
    int res_off = 0;

    const int lo = (w == 0) ? 2 : (64 * w - 1);  // -1 pre-step seeds nb1
    const int hi = 64 * w + 63 + (N - 1);        // 64w + 1086
    int d0 = 2 - K * w;                          // diag of step k=0, epoch 0

    // Contour window: cw[k] = contour[(d0+k - t) mod N]; wrapped entries are
    // in-bounds garbage, neutralized by the k2=0 select.
    float2 cw[K];
    #pragma unroll
    for (int k = 0; k < K; ++k)
        cw[k] = cg[(unsigned)(d0 + k - t) & (N - 1)];

    double rvc[K];                               // converted ring (lane 0)
    #pragma unroll
    for (int k = 0; k < K; ++k) rvc[k] = 0.0;
    double wb[K];                                // boundary values (lane 63)

    for (int g = 0; g < NGRP; ++g) {
        const bool overlap = (d0 <= hi) && (d0 + (K - 1) >= lo);
        if (overlap) {
            // Epoch-start: ring read + conversion to my offset (off-chain).
            if (w > 0) {
                int oin = ringo[w - 1][(g ^ 1) & 1];       // wave-uniform
                if (!adopted) { off = oin; adopted = true; }
                if (lane == 0) {
                    int dl = off - oin;
                    int c1 = min(max(dl, -1022), 1022);
                    int c2 = min(max(dl - c1, -1022), 1022);
                    double f1 = pow2d(c1), f2 = pow2d(c2);
                    const double* p = &ringv[w - 1][(g ^ 1) & 1][0];
                    #pragma unroll
                    for (int k = 0; k < K; ++k)
                        rvc[k] = (p[k] * f1) * f2;
                }
            }

            // Off-chain: the 8 step factors 2^(-cost*log2e); inactive -> 0.
            double k2[K];
            #pragma unroll
            for (int k = 0; k < K; ++k) {
                const int dk = d0 + k;
                const bool act = (unsigned)(dk - t) < (unsigned)N;
                float dx = sp.x - cw[k].x;
                float dy = sp.y - cw[k].y;
                float cost = dx * dx + dy * dy;
                float e = __builtin_amdgcn_exp2f(cost * (-L2E));
                k2[k] = act ? (double)e : 0.0;
            }
            const int kres = (t + N - 1) - d0;   // step index of my last cell

            // The chain: add+add+mul (f64) + DPP + selects per step.
            // Inactive cells: k2=0 -> zn=0, so pre-start and finished lanes
            // hold exactly 0 (excluded from rescale max automatically).
            #pragma unroll
            for (int k = 0; k < K; ++k) {
                double zn = k2[k] * ((nb2 + nb1) + cur);
                wb[k] = zn;
                if (k == kres) { res = zn; res_off = off; } // final-cell snap
                cur = zn;
                double a  = dpp_movd<0x111>(zn);  // row_shr:1
                double bc = dpp_movd<0x142>(zn);  // row_bcast15
                double up = ((t & 15) == 0) ? bc : a;
                nb2 = nb1;
                nb1 = (lane == 0) ? rvc[k] : up;
            }

            // Ring write: raw fp64 boundary values at my (pre-rescale) off.
            if (lane == 63) {
                #pragma unroll
                for (int k = 0; k < K; ++k) ringv[w][g & 1][k] = wb[k];
                ringo[w][g & 1] = off;
            }

            // Per-wave exact power-of-2 rescale: wave-max exponent -> 2^0.
            int e = (int)((__double_as_longlong(cur) >> 52) & 0x7FF);
            #pragma unroll
            for (int i = 1; i < 64; i <<= 1)
                e = max(e, __shfl_xor(e, i));
            if (e > 0) {                          // wave-uniform branch
                int sh = 1023 - e;
                int c1 = min(max(sh, -1022), 1022);
                int c2 = min(max(sh - c1, -1022), 1022);
                double f1 = pow2d(c1), f2 = pow2d(c2);
                cur = (cur * f1) * f2;
                nb1 = (nb1 * f1) * f2;
                nb2 = (nb2 * f1) * f2;
                off += sh;
            }
        }

        d0 += K;

        // Prefetch contour window for the next epoch (hidden under barrier).
        #pragma unroll
        for (int k = 0; k < K; ++k)
            cw[k] = cg[(unsigned)(d0 + k - t) & (N - 1)];

        __syncthreads();
    }

    // Thread 1023: res = Z of R[1023,1023] at offset res_off (exact snap).
    if (t == TPB - 1) {
        double R = ((double)res_off - log2(res)) * LN2D;
        atomicAdd(out, (float)(R * (1.0 / 64.0)));
    }
}

extern "C" void kernel_launch(void* const* d_in, const int* in_sizes, int n_in,
                              void* d_out, int out_size, void* d_ws, size_t ws_size,
                              hipStream_t stream) {
    const float2* snake   = (const float2*)d_in[0];
    const float2* contour = (const float2*)d_in[1];
    float* out = (float*)d_out;
    // Harness re-poisons d_out to 0xAA before every timed launch.
    hipMemsetAsync(out, 0, sizeof(float), stream);
    dtw_kernel<<<64, TPB, 0, stream>>>(snake, contour, out);
}